// Round 1
// baseline (1378.687 us; speedup 1.0000x reference)
//
#include <hip/hip_runtime.h>
#include <math.h>

#define NSLOTS 50
#define T 101
#define SEQ 2048

__device__ inline float wave_max_f(float v) {
    #pragma unroll
    for (int m = 32; m > 0; m >>= 1) v = fmaxf(v, __shfl_xor(v, m, 64));
    return v;
}
__device__ inline float wave_sum_f(float v) {
    #pragma unroll
    for (int m = 32; m > 0; m >>= 1) v += __shfl_xor(v, m, 64);
    return v;
}
__device__ inline int wave_sum_i(int v) {
    #pragma unroll
    for (int m = 32; m > 0; m >>= 1) v += __shfl_xor(v, m, 64);
    return v;
}

// trans(i,j) from the analytic rule:
// class: tag==0 -> O(0); odd -> B(1); even -> I(2)
// t0 = m1[class_i]; t1 = (i!='O' && slot_i!=slot_j) ? m2[class_j] : m1[class_j]
// m1 = {O:0,B:1,I:2}; m2 = {O:0,B:3,I:4}
__device__ inline float trans_val(const float* L, int i, int j) {
    int ci = (i == 0) ? 0 : ((i & 1) ? 1 : 2);
    int cj = (j == 0) ? 0 : ((j & 1) ? 1 : 2);
    int si = (i - 1) >> 1;   // -1 for i==0 (guarded by ci!=0 check)
    int sj = (j - 1) >> 1;   // -1 for j==0 -> differs from any si>=0; m2[O]==m1[O]==0 anyway
    int t1 = (i != 0 && si != sj) ? ((cj == 0) ? 0 : cj + 2) : cj;
    return L[ci * 5 + t1];
}

__global__ __launch_bounds__(64) void crf_nll_kernel(
    const float* __restrict__ feats,      // [B,S,T]
    const float* __restrict__ cdt,        // [3,5] log-probs
    const float* __restrict__ start_t,    // [T]
    const float* __restrict__ stop_t,     // [T]
    const int*   __restrict__ mask,       // [B,S]
    const int*   __restrict__ tags,       // [B,S]
    float*       __restrict__ out)        // [B]
{
    const int b = blockIdx.x;
    const int l = threadIdx.x;
    const float* fb = feats + (size_t)b * SEQ * T;
    const int*   mb = mask + (size_t)b * SEQ;
    const int*   tb = tags + (size_t)b * SEQ;

    // cdt log values (15 floats) and exp'd probabilities we need
    float L[15];
    #pragma unroll
    for (int i = 0; i < 15; ++i) L[i] = cdt[i];
    const float pOB = __expf(L[0*5+1]), pBBs = __expf(L[1*5+1]), pBBd = __expf(L[1*5+3]),
                pIBs = __expf(L[2*5+1]), pIBd = __expf(L[2*5+3]);
    const float pOI = __expf(L[0*5+2]), pBIs = __expf(L[1*5+2]), pBId = __expf(L[1*5+4]),
                pIIs = __expf(L[2*5+2]), pIId = __expf(L[2*5+4]);
    const float pOO = __expf(L[0*5+0]), pBO  = __expf(L[1*5+0]), pIO  = __expf(L[2*5+0]);

    // ---------- gold score: t-parallel across the wave ----------
    float gs = 0.f;
    int mcount = 0;
    for (int t = l; t < SEQ; t += 64) {
        int mk = mb[t];
        mcount += mk;
        if (mk) {
            int tg = tb[t];
            gs += fb[(size_t)t * T + tg];
            if (t >= 1) gs += trans_val(L, tb[t - 1], tg);
        }
    }
    float gold = wave_sum_f(gs);
    int len = wave_sum_i(mcount);   // mask is a prefix of ones

    // ---------- forward scan: lane l owns slot l (tags 2l+1, 2l+2) ----------
    const bool act = (l < NSLOTS);
    const int tagB = 2 * l + 1;
    const int tagI = 2 * l + 2;

    float pB = act ? fb[tagB] + start_t[tagB] : -INFINITY;
    float pI = act ? fb[tagI] + start_t[tagI] : -INFINITY;
    float pO = fb[0] + start_t[0];   // replicated across lanes

    // prefetch t=1 feats
    const float* fr1 = fb + T;
    float fB = act ? fr1[tagB] : 0.f;
    float fI = act ? fr1[tagI] : 0.f;
    float fO = fr1[0];

    for (int t = 1; t < len; ++t) {
        // prefetch next step's feats (independent of the reduction chain)
        float nfB = 0.f, nfI = 0.f, nfO = 0.f;
        if (t + 1 < len) {
            const float* f2 = fb + (size_t)(t + 1) * T;
            nfB = act ? f2[tagB] : 0.f;
            nfI = act ? f2[tagI] : 0.f;
            nfO = f2[0];
        }

        float M = fmaxf(wave_max_f(fmaxf(pB, pI)), pO);
        float eB = act ? __expf(pB - M) : 0.f;
        float eI = act ? __expf(pI - M) : 0.f;
        float eO = __expf(pO - M);
        float SB = wave_sum_f(eB);
        float SI = wave_sum_f(eI);
        float sb = SB - eB, si = SI - eI;

        float nB = fB + M + __logf(eO * pOB + sb * pBBd + eB * pBBs + si * pIBd + eI * pIBs);
        float nI = fI + M + __logf(eO * pOI + sb * pBId + eB * pBIs + si * pIId + eI * pIIs);
        float nO = fO + M + __logf(eO * pOO + SB * pBO  + SI * pIO);

        if (act) { pB = nB; pI = nI; }
        pO = nO;
        fB = nfB; fI = nfI; fO = nfO;
    }

    // ---------- forward_score = LSE_j(partition[j] + stop[j]) ----------
    float sB2 = act ? pB + stop_t[tagB] : -INFINITY;
    float sI2 = act ? pI + stop_t[tagI] : -INFINITY;
    float sO2 = pO + stop_t[0];
    float M2 = fmaxf(wave_max_f(fmaxf(sB2, sI2)), sO2);
    float es = act ? __expf(sB2 - M2) + __expf(sI2 - M2) : 0.f;
    float sum2 = wave_sum_f(es) + __expf(sO2 - M2);
    float fwd = M2 + __logf(sum2);

    gold += start_t[tb[0]] + stop_t[tb[len - 1]];

    if (l == 0) out[b] = fwd - gold;
}

extern "C" void kernel_launch(void* const* d_in, const int* in_sizes, int n_in,
                              void* d_out, int out_size, void* d_ws, size_t ws_size,
                              hipStream_t stream) {
    const float* feats   = (const float*)d_in[0];
    const float* cdt     = (const float*)d_in[1];
    const float* start_t = (const float*)d_in[2];
    const float* stop_t  = (const float*)d_in[3];
    const int*   mask    = (const int*)d_in[4];
    const int*   tags    = (const int*)d_in[5];
    // d_in[6], d_in[7] (types0/types1) unused: transition rule derived analytically
    float* out = (float*)d_out;

    crf_nll_kernel<<<256, 64, 0, stream>>>(feats, cdt, start_t, stop_t, mask, tags, out);
}

// Round 2
// 1103.405 us; speedup vs baseline: 1.2495x; 1.2495x over previous
//
#include <hip/hip_runtime.h>
#include <math.h>

#define NSLOTS 50
#define T 101
#define SEQ 2048
#define PFD 8

__device__ inline float wave_max_f(float v) {
    #pragma unroll
    for (int m = 32; m > 0; m >>= 1) v = fmaxf(v, __shfl_xor(v, m, 64));
    return v;
}
__device__ inline float wave_sum_f(float v) {
    #pragma unroll
    for (int m = 32; m > 0; m >>= 1) v += __shfl_xor(v, m, 64);
    return v;
}
__device__ inline int wave_sum_i(int v) {
    #pragma unroll
    for (int m = 32; m > 0; m >>= 1) v += __shfl_xor(v, m, 64);
    return v;
}

// v + permuted(v) via DPP (VALU latency, no LDS)
template<int CTRL>
__device__ inline float dpp_xadd(float v) {
    int x = __builtin_amdgcn_update_dpp(0, __float_as_int(v), CTRL, 0xF, 0xF, true);
    return v + __int_as_float(x);
}

// full 64-lane sum, result uniform in all lanes, pure VALU
__device__ inline float bfly_sum64(float v) {
    v = dpp_xadd<0xB1>(v);   // quad_perm [1,0,3,2]  : pair sums
    v = dpp_xadd<0x4E>(v);   // quad_perm [2,3,0,1]  : 4-group sums
    v = dpp_xadd<0x141>(v);  // row_half_mirror      : 8-group sums
    v = dpp_xadd<0x140>(v);  // row_mirror           : 16-row sums
#if __has_builtin(__builtin_amdgcn_permlane16_swap)
    {
        auto r = __builtin_amdgcn_permlane16_swap(
            (unsigned)__float_as_int(v), (unsigned)__float_as_int(v), false, false);
        // one element holds own value, the other the partner row's: sum = own+partner
        v = __int_as_float((int)r[0]) + __int_as_float((int)r[1]);
    }
#else
    v += __int_as_float(__builtin_amdgcn_ds_swizzle(__float_as_int(v), 0x401F)); // xor 16
#endif
#if __has_builtin(__builtin_amdgcn_permlane32_swap)
    {
        auto r = __builtin_amdgcn_permlane32_swap(
            (unsigned)__float_as_int(v), (unsigned)__float_as_int(v), false, false);
        v = __int_as_float((int)r[0]) + __int_as_float((int)r[1]);
    }
#else
    v += __shfl_xor(v, 32, 64);
#endif
    return v;
}

// analytic transition rule (for gold score)
__device__ inline float trans_val(const float* L, int i, int j) {
    int ci = (i == 0) ? 0 : ((i & 1) ? 1 : 2);
    int cj = (j == 0) ? 0 : ((j & 1) ? 1 : 2);
    int si = (i - 1) >> 1;
    int sj = (j - 1) >> 1;
    int t1 = (i != 0 && si != sj) ? ((cj == 0) ? 0 : cj + 2) : cj;
    return L[ci * 5 + t1];
}

__global__ __launch_bounds__(64) void crf_nll_kernel(
    const float* __restrict__ feats,      // [B,S,T]
    const float* __restrict__ cdt,        // [3,5] log-probs
    const float* __restrict__ start_t,    // [T]
    const float* __restrict__ stop_t,     // [T]
    const int*   __restrict__ mask,       // [B,S]
    const int*   __restrict__ tags,       // [B,S]
    float*       __restrict__ out)        // [B]
{
    const int b = blockIdx.x;
    const int l = threadIdx.x;
    const float* fb = feats + (size_t)b * SEQ * T;
    const int*   mb = mask + (size_t)b * SEQ;
    const int*   tb = tags + (size_t)b * SEQ;

    float L[15];
    #pragma unroll
    for (int i = 0; i < 15; ++i) L[i] = cdt[i];
    // probabilities (row = class of i: O,B,I ; col: O, B-same, I-same, B-diff, I-diff)
    const float pOO = __expf(L[0]),  pOB = __expf(L[1]),  pOI = __expf(L[2]);
    const float pBO = __expf(L[5]),  pBBs = __expf(L[6]), pBIs = __expf(L[7]),
                pBBd = __expf(L[8]), pBId = __expf(L[9]);
    const float pIO = __expf(L[10]), pIBs = __expf(L[11]), pIIs = __expf(L[12]),
                pIBd = __expf(L[13]), pIId = __expf(L[14]);
    // deltas so e-terms fold in before the wave sums complete
    const float dBB = pBBs - pBBd, dIB = pIBs - pIBd;   // for zB: coeff of eB, eI
    const float dBI = pBIs - pBId, dII = pIIs - pIId;   // for zI

    // ---------- gold score: t-parallel across the wave ----------
    float gs = 0.f;
    int mcount = 0;
    for (int t = l; t < SEQ; t += 64) {
        int mk = mb[t];
        mcount += mk;
        if (mk) {
            int tg = tb[t];
            gs += fb[(size_t)t * T + tg];
            if (t >= 1) gs += trans_val(L, tb[t - 1], tg);
        }
    }
    float gold = wave_sum_f(gs);
    int len = wave_sum_i(mcount);   // mask is a prefix of ones

    // ---------- forward scan: lane l owns slot l (tags 2l+1, 2l+2) ----------
    const bool act = (l < NSLOTS);
    const int tagB = 2 * l + 1;
    const int tagI = 2 * l + 2;

    // relative state: rB = pB - pO, rI = pI - pO ; accO = absolute pO
    float p0O = fb[0] + start_t[0];
    float rB = act ? (fb[tagB] + start_t[tagB]) - p0O : -INFINITY;
    float rI = act ? (fb[tagI] + start_t[tagI]) - p0O : -INFINITY;
    float accO = p0O;

    // register ring buffer, depth PFD, static indexing only
    float bB[PFD], bI[PFD], bO[PFD];
    #pragma unroll
    for (int k = 0; k < PFD; ++k) {
        int t = 1 + k;
        int tc = (t < SEQ) ? t : 0;
        const float* f = fb + (size_t)tc * T;
        bB[k] = act ? f[tagB] : 0.f;
        bI[k] = act ? f[tagI] : 0.f;
        bO[k] = f[0];
    }

    int t = 1;
    while (t < len) {
        #pragma unroll
        for (int k = 0; k < PFD; ++k) {
            if (t >= len) break;
            float fB = bB[k], fI = bI[k], fO = bO[k];
            // prefetch step t+PFD into this slot
            {
                int tp = t + PFD;
                int tc = (tp < SEQ) ? tp : 0;
                const float* f = fb + (size_t)tc * T;
                bB[k] = act ? f[tagB] : 0.f;
                bI[k] = act ? f[tagI] : 0.f;
                bO[k] = f[0];
            }

            float eB = act ? __expf(rB) : 0.f;
            float eI = act ? __expf(rI) : 0.f;
            float SB = bfly_sum64(eB);
            float SI = bfly_sum64(eI);
            // off-chain partials (overlap with butterfly)
            float uB = pOB + eB * dBB + eI * dIB;
            float uI = pOI + eB * dBI + eI * dII;
            float dfB = fB - fO;
            float dfI = fI - fO;

            float zB = uB + SB * pBBd + SI * pIBd;
            float zI = uI + SB * pBId + SI * pIId;
            float zO = pOO + SB * pBO + SI * pIO;
            float lO = __logf(zO);
            if (act) {
                rB = dfB + (__logf(zB) - lO);
                rI = dfI + (__logf(zI) - lO);
            }
            accO += fO + lO;
            ++t;
        }
    }

    // ---------- forward_score = LSE_j(partition[j] + stop[j]) ----------
    float sB2 = act ? accO + rB + stop_t[tagB] : -INFINITY;
    float sI2 = act ? accO + rI + stop_t[tagI] : -INFINITY;
    float sO2 = accO + stop_t[0];
    float M2 = fmaxf(wave_max_f(fmaxf(sB2, sI2)), sO2);
    float es = act ? __expf(sB2 - M2) + __expf(sI2 - M2) : 0.f;
    float sum2 = wave_sum_f(es) + __expf(sO2 - M2);
    float fwd = M2 + __logf(sum2);

    gold += start_t[tb[0]] + stop_t[tb[len - 1]];

    if (l == 0) out[b] = fwd - gold;
}

extern "C" void kernel_launch(void* const* d_in, const int* in_sizes, int n_in,
                              void* d_out, int out_size, void* d_ws, size_t ws_size,
                              hipStream_t stream) {
    const float* feats   = (const float*)d_in[0];
    const float* cdt     = (const float*)d_in[1];
    const float* start_t = (const float*)d_in[2];
    const float* stop_t  = (const float*)d_in[3];
    const int*   mask    = (const int*)d_in[4];
    const int*   tags    = (const int*)d_in[5];
    float* out = (float*)d_out;

    crf_nll_kernel<<<256, 64, 0, stream>>>(feats, cdt, start_t, stop_t, mask, tags, out);
}

// Round 3
// 813.223 us; speedup vs baseline: 1.6953x; 1.3568x over previous
//
#include <hip/hip_runtime.h>
#include <math.h>

#define NSLOTS 50
#define T 101
#define SEQ 2048
#define PFD 16

// v + dpp_permuted(v), pure VALU
template<int CTRL>
__device__ inline float dpp_xadd(float v) {
    int x = __builtin_amdgcn_update_dpp(0, __float_as_int(v), CTRL, 0xF, 0xF, true);
    return v + __int_as_float(x);
}

// full 64-lane sum, result uniform in all lanes, no LDS
__device__ inline float bfly_sum64(float v) {
    v = dpp_xadd<0xB1>(v);   // quad_perm [1,0,3,2]
    v = dpp_xadd<0x4E>(v);   // quad_perm [2,3,0,1]
    v = dpp_xadd<0x141>(v);  // row_half_mirror
    v = dpp_xadd<0x140>(v);  // row_mirror
#if __has_builtin(__builtin_amdgcn_permlane16_swap)
    {
        auto r = __builtin_amdgcn_permlane16_swap(
            (unsigned)__float_as_int(v), (unsigned)__float_as_int(v), false, false);
        v = __int_as_float((int)r[0]) + __int_as_float((int)r[1]);
    }
#else
    v += __int_as_float(__builtin_amdgcn_ds_swizzle(__float_as_int(v), 0x401F));
#endif
#if __has_builtin(__builtin_amdgcn_permlane32_swap)
    {
        auto r = __builtin_amdgcn_permlane32_swap(
            (unsigned)__float_as_int(v), (unsigned)__float_as_int(v), false, false);
        v = __int_as_float((int)r[0]) + __int_as_float((int)r[1]);
    }
#else
    v += __shfl_xor(v, 32, 64);
#endif
    return v;
}

// analytic transition rule (gold score only)
__device__ inline float trans_val(const float* L, int i, int j) {
    int ci = (i == 0) ? 0 : ((i & 1) ? 1 : 2);
    int cj = (j == 0) ? 0 : ((j & 1) ? 1 : 2);
    int si = (i - 1) >> 1;
    int sj = (j - 1) >> 1;
    int t1 = (i != 0 && si != sj) ? ((cj == 0) ? 0 : cj + 2) : cj;
    return L[ci * 5 + t1];
}

__global__ __launch_bounds__(64) void crf_nll_kernel(
    const float* __restrict__ feats,      // [B,S,T]
    const float* __restrict__ cdt,        // [3,5] log-probs
    const float* __restrict__ start_t,    // [T]
    const float* __restrict__ stop_t,     // [T]
    const int*   __restrict__ mask,       // [B,S]
    const int*   __restrict__ tags,       // [B,S]
    float*       __restrict__ out)        // [B]
{
    const int b = blockIdx.x;
    const int l = threadIdx.x;
    const float* fb = feats + (size_t)b * SEQ * T;
    const int*   mb = mask + (size_t)b * SEQ;
    const int*   tb = tags + (size_t)b * SEQ;

    float L[15];
    #pragma unroll
    for (int i = 0; i < 15; ++i) L[i] = cdt[i];
    const float pOO = __expf(L[0]),  pOB = __expf(L[1]),  pOI = __expf(L[2]);
    const float pBO = __expf(L[5]),  pBBs = __expf(L[6]), pBIs = __expf(L[7]),
                pBBd = __expf(L[8]), pBId = __expf(L[9]);
    const float pIO = __expf(L[10]), pIBs = __expf(L[11]), pIIs = __expf(L[12]),
                pIBd = __expf(L[13]), pIId = __expf(L[14]);
    const float dBB = pBBs - pBBd, dIB = pIBs - pIBd;
    const float dBI = pBIs - pBId, dII = pIIs - pIId;

    // ---------- gold score + length: t-parallel ----------
    float gs = 0.f, mc = 0.f;
    for (int t = l; t < SEQ; t += 64) {
        int mk = mb[t];
        mc += (float)mk;
        if (mk) {
            int tg = tb[t];
            gs += fb[(size_t)t * T + tg];
            if (t >= 1) gs += trans_val(L, tb[t - 1], tg);
        }
    }
    float gold = bfly_sum64(gs);
    const int len = (int)(bfly_sum64(mc) + 0.5f);   // mask is a prefix of ones

    // ---------- forward scan in exponent-ratio domain ----------
    const bool act = (l < NSLOTS);
    const int aB = (2 * l + 1 < T) ? 2 * l + 1 : T - 1;   // clamped, memory-safe for l>=50
    const int aI = (2 * l + 2 < T) ? 2 * l + 2 : T - 1;

    // t=0 state: eO == 1 by construction
    float f0O = fb[0] + start_t[0];
    float eB = act ? __expf((fb[aB] + start_t[aB]) - f0O) : 0.f;
    float eI = act ? __expf((fb[aI] + start_t[aI]) - f0O) : 0.f;
    float accO = f0O;    // absolute log-scale (O component)
    float accL = 0.f;    // sum of log2(zO)

    // register ring buffer: g-factors exp(f-fO) and raw fO, static indexing only
    float rgB[PFD], rgI[PFD], rfO[PFD];
    #pragma unroll
    for (int k = 0; k < PFD; ++k) {
        const float* f = fb + (size_t)(1 + k) * T;   // len >= 1024 > PFD: always real steps
        float fO = f[0];
        rgB[k] = act ? __expf(f[aB] - fO) : 0.f;
        rgI[k] = act ? __expf(f[aI] - fO) : 0.f;
        rfO[k] = fO;
    }

    const int nsteps = len - 1;                 // scan steps t = 1 .. len-1
    const int nmain  = (nsteps / PFD) * PFD;

    for (int c = 0; c < nmain; c += PFD) {
        #pragma unroll
        for (int k = 0; k < PFD; ++k) {
            float gB = rgB[k], gI = rgI[k], fO = rfO[k];
            // prefetch step (c+1+k) + PFD  (off the dependent chain)
            {
                int tp = c + 1 + k + PFD;
                tp = (tp < SEQ) ? tp : (SEQ - 1);
                const float* f = fb + (size_t)tp * T;
                float nfO = f[0];
                rgB[k] = act ? __expf(f[aB] - nfO) : 0.f;
                rgI[k] = act ? __expf(f[aI] - nfO) : 0.f;
                rfO[k] = nfO;
            }

            float SB = bfly_sum64(eB);
            float SI = bfly_sum64(eI);
            float uB = pOB + eB * dBB + eI * dIB;   // overlaps with butterflies
            float uI = pOI + eB * dBI + eI * dII;
            float zB = uB + SB * pBBd + SI * pIBd;
            float zI = uI + SB * pBId + SI * pIId;
            float zO = pOO + SB * pBO + SI * pIO;
#if __has_builtin(__builtin_amdgcn_rcpf)
            float rz = __builtin_amdgcn_rcpf(zO);
#else
            float rz = 1.0f / zO;
#endif
            eB = (gB * zB) * rz;
            eI = (gI * zI) * rz;
            accL += __log2f(zO);   // off-chain
            accO += fO;            // off-chain
        }
    }

    // tail: rem <= PFD-1 steps already sitting in ring slots 0..rem-1
    {
        const int rem = nsteps - nmain;
        #pragma unroll
        for (int k = 0; k < PFD; ++k) {
            if (k < rem) {
                float gB = rgB[k], gI = rgI[k], fO = rfO[k];
                float SB = bfly_sum64(eB);
                float SI = bfly_sum64(eI);
                float uB = pOB + eB * dBB + eI * dIB;
                float uI = pOI + eB * dBI + eI * dII;
                float zB = uB + SB * pBBd + SI * pIBd;
                float zI = uI + SB * pBId + SI * pIId;
                float zO = pOO + SB * pBO + SI * pIO;
#if __has_builtin(__builtin_amdgcn_rcpf)
                float rz = __builtin_amdgcn_rcpf(zO);
#else
                float rz = 1.0f / zO;
#endif
                eB = (gB * zB) * rz;
                eI = (gI * zI) * rz;
                accL += __log2f(zO);
                accO += fO;
            }
        }
    }

    accO += accL * 0.6931471805599453f;

    // ---------- forward_score = accO + log( sum_j e_j * exp(stop_j) ) ----------
    float wsum = act ? eB * __expf(stop_t[aB]) + eI * __expf(stop_t[aI]) : 0.f;
    float sum2 = bfly_sum64(wsum) + __expf(stop_t[0]);   // eO == 1
    float fwd = accO + __logf(sum2);

    gold += start_t[tb[0]] + stop_t[tb[len - 1]];

    if (l == 0) out[b] = fwd - gold;
}

extern "C" void kernel_launch(void* const* d_in, const int* in_sizes, int n_in,
                              void* d_out, int out_size, void* d_ws, size_t ws_size,
                              hipStream_t stream) {
    const float* feats   = (const float*)d_in[0];
    const float* cdt     = (const float*)d_in[1];
    const float* start_t = (const float*)d_in[2];
    const float* stop_t  = (const float*)d_in[3];
    const int*   mask    = (const int*)d_in[4];
    const int*   tags    = (const int*)d_in[5];
    float* out = (float*)d_out;

    crf_nll_kernel<<<256, 64, 0, stream>>>(feats, cdt, start_t, stop_t, mask, tags, out);
}

// Round 4
// 327.263 us; speedup vs baseline: 4.2128x; 2.4849x over previous
//
#include <hip/hip_runtime.h>
#include <math.h>

#define NSLOTS 50
#define T 101
#define SEQ 2048
#define PFD 24

// v + dpp_permuted(v), pure VALU
template<int CTRL>
__device__ inline float dpp_xadd(float v) {
    int x = __builtin_amdgcn_update_dpp(0, __float_as_int(v), CTRL, 0xF, 0xF, true);
    return v + __int_as_float(x);
}

// full 64-lane sum, result uniform in all lanes, no LDS
__device__ inline float bfly_sum64(float v) {
    v = dpp_xadd<0xB1>(v);   // quad_perm [1,0,3,2]
    v = dpp_xadd<0x4E>(v);   // quad_perm [2,3,0,1]
    v = dpp_xadd<0x141>(v);  // row_half_mirror
    v = dpp_xadd<0x140>(v);  // row_mirror
#if __has_builtin(__builtin_amdgcn_permlane16_swap)
    {
        auto r = __builtin_amdgcn_permlane16_swap(
            (unsigned)__float_as_int(v), (unsigned)__float_as_int(v), false, false);
        v = __int_as_float((int)r[0]) + __int_as_float((int)r[1]);
    }
#else
    v += __int_as_float(__builtin_amdgcn_ds_swizzle(__float_as_int(v), 0x401F));
#endif
#if __has_builtin(__builtin_amdgcn_permlane32_swap)
    {
        auto r = __builtin_amdgcn_permlane32_swap(
            (unsigned)__float_as_int(v), (unsigned)__float_as_int(v), false, false);
        v = __int_as_float((int)r[0]) + __int_as_float((int)r[1]);
    }
#else
    v += __shfl_xor(v, 32, 64);
#endif
    return v;
}

// analytic transition rule (gold score only)
__device__ inline float trans_val(const float* L, int i, int j) {
    int ci = (i == 0) ? 0 : ((i & 1) ? 1 : 2);
    int cj = (j == 0) ? 0 : ((j & 1) ? 1 : 2);
    int si = (i - 1) >> 1;
    int sj = (j - 1) >> 1;
    int t1 = (i != 0 && si != sj) ? ((cj == 0) ? 0 : cj + 2) : cj;
    return L[ci * 5 + t1];
}

__global__ __launch_bounds__(64, 1) void crf_nll_kernel(
    const float* __restrict__ feats,      // [B,S,T]
    const float* __restrict__ cdt,        // [3,5] log-probs
    const float* __restrict__ start_t,    // [T]
    const float* __restrict__ stop_t,     // [T]
    const int*   __restrict__ mask,       // [B,S]
    const int*   __restrict__ tags,       // [B,S]
    float*       __restrict__ out)        // [B]
{
    const int b = blockIdx.x;
    const int l = threadIdx.x;
    const float* fb = feats + (size_t)b * SEQ * T;
    const int*   mb = mask + (size_t)b * SEQ;
    const int*   tb = tags + (size_t)b * SEQ;

    float L[15];
    #pragma unroll
    for (int i = 0; i < 15; ++i) L[i] = cdt[i];
    const float pOO = __expf(L[0]),  pOB = __expf(L[1]),  pOI = __expf(L[2]);
    const float pBO = __expf(L[5]),  pBBs = __expf(L[6]), pBIs = __expf(L[7]),
                pBBd = __expf(L[8]), pBId = __expf(L[9]);
    const float pIO = __expf(L[10]), pIBs = __expf(L[11]), pIIs = __expf(L[12]),
                pIBd = __expf(L[13]), pIId = __expf(L[14]);
    const float dBB = pBBs - pBBd, dIB = pIBs - pIBd;
    const float dBI = pBIs - pBId, dII = pIIs - pIId;

    // ---------- gold score + length: t-parallel ----------
    float gs = 0.f, mc = 0.f;
    for (int t = l; t < SEQ; t += 64) {
        int mk = mb[t];
        mc += (float)mk;
        if (mk) {
            int tg = tb[t];
            gs += fb[(size_t)t * T + tg];
            if (t >= 1) gs += trans_val(L, tb[t - 1], tg);
        }
    }
    float gold = bfly_sum64(gs);
    const int len = (int)(bfly_sum64(mc) + 0.5f);   // mask is a prefix of ones

    // ---------- forward scan in exponent-ratio domain ----------
    const bool act = (l < NSLOTS);
    const int aB = (2 * l + 1 < T) ? 2 * l + 1 : T - 1;   // clamped, memory-safe for l>=50
    const int aI = (2 * l + 2 < T) ? 2 * l + 2 : T - 1;

    // t=0 state: eO == 1 by construction
    float f0O = fb[0] + start_t[0];
    float eB = act ? __expf((fb[aB] + start_t[aB]) - f0O) : 0.f;
    float eI = act ? __expf((fb[aI] + start_t[aI]) - f0O) : 0.f;
    float accO = f0O;    // absolute log-scale (O component)
    float accL = 0.f;    // sum of log2(zO)

    // register ring buffer of RAW feats (no load-dependent VALU at prefetch site)
    float rB_[PFD], rI_[PFD], rO_[PFD];
    #pragma unroll
    for (int k = 0; k < PFD; ++k) {
        const float* f = fb + (size_t)(1 + k) * T;   // len >= 1024 > PFD: always real
        rB_[k] = f[aB];
        rI_[k] = f[aI];
        rO_[k] = f[0];
    }

    const int nsteps = len - 1;                 // scan steps t = 1 .. len-1
    const int nmain  = (nsteps / PFD) * PFD;

    for (int c = 0; c < nmain; c += PFD) {
        #pragma unroll
        for (int k = 0; k < PFD; ++k) {
            float fB = rB_[k], fI = rI_[k], fO = rO_[k];
            // prefetch step (c+1+k) + PFD : pure loads, nothing depends on them here
            {
                int tp = c + 1 + k + PFD;
                tp = (tp < SEQ) ? tp : (SEQ - 1);
                const float* f = fb + (size_t)tp * T;
                rB_[k] = f[aB];
                rI_[k] = f[aI];
                rO_[k] = f[0];
            }

            float gB = act ? __expf(fB - fO) : 0.f;   // off-chain
            float gI = act ? __expf(fI - fO) : 0.f;

            float SB = bfly_sum64(eB);
            float SI = bfly_sum64(eI);
            float uB = pOB + eB * dBB + eI * dIB;     // overlaps butterflies
            float uI = pOI + eB * dBI + eI * dII;
            float zB = uB + SB * pBBd + SI * pIBd;
            float zI = uI + SB * pBId + SI * pIId;
            float zO = pOO + SB * pBO + SI * pIO;
#if __has_builtin(__builtin_amdgcn_rcpf)
            float rz = __builtin_amdgcn_rcpf(zO);
#else
            float rz = 1.0f / zO;
#endif
            eB = (gB * zB) * rz;
            eI = (gI * zI) * rz;
            accL += __log2f(zO);   // off-chain
            accO += fO;            // off-chain
        }
    }

    // tail: rem <= PFD-1 steps already sitting in ring slots 0..rem-1
    {
        const int rem = nsteps - nmain;
        #pragma unroll
        for (int k = 0; k < PFD; ++k) {
            if (k < rem) {
                float fB = rB_[k], fI = rI_[k], fO = rO_[k];
                float gB = act ? __expf(fB - fO) : 0.f;
                float gI = act ? __expf(fI - fO) : 0.f;
                float SB = bfly_sum64(eB);
                float SI = bfly_sum64(eI);
                float uB = pOB + eB * dBB + eI * dIB;
                float uI = pOI + eB * dBI + eI * dII;
                float zB = uB + SB * pBBd + SI * pIBd;
                float zI = uI + SB * pBId + SI * pIId;
                float zO = pOO + SB * pBO + SI * pIO;
#if __has_builtin(__builtin_amdgcn_rcpf)
                float rz = __builtin_amdgcn_rcpf(zO);
#else
                float rz = 1.0f / zO;
#endif
                eB = (gB * zB) * rz;
                eI = (gI * zI) * rz;
                accL += __log2f(zO);
                accO += fO;
            }
        }
    }

    accO += accL * 0.6931471805599453f;

    // ---------- forward_score = accO + log( sum_j e_j * exp(stop_j) ) ----------
    float wsum = act ? eB * __expf(stop_t[aB]) + eI * __expf(stop_t[aI]) : 0.f;
    float sum2 = bfly_sum64(wsum) + __expf(stop_t[0]);   // eO == 1
    float fwd = accO + __logf(sum2);

    gold += start_t[tb[0]] + stop_t[tb[len - 1]];

    if (l == 0) out[b] = fwd - gold;
}

extern "C" void kernel_launch(void* const* d_in, const int* in_sizes, int n_in,
                              void* d_out, int out_size, void* d_ws, size_t ws_size,
                              hipStream_t stream) {
    const float* feats   = (const float*)d_in[0];
    const float* cdt     = (const float*)d_in[1];
    const float* start_t = (const float*)d_in[2];
    const float* stop_t  = (const float*)d_in[3];
    const int*   mask    = (const int*)d_in[4];
    const int*   tags    = (const int*)d_in[5];
    float* out = (float*)d_out;

    crf_nll_kernel<<<256, 64, 0, stream>>>(feats, cdt, start_t, stop_t, mask, tags, out);
}